// Round 1
// 240.645 us; speedup vs baseline: 1.0628x; 1.0628x over previous
//
#include <hip/hip_runtime.h>
#include <hip/hip_bf16.h>
#include <math.h>

typedef __bf16 bf16x8v __attribute__((ext_vector_type(8)));
typedef __bf16 bf16x4v __attribute__((ext_vector_type(4)));
typedef float  f32x4   __attribute__((ext_vector_type(4)));

#define D_DIM 512
#define P_DIM 128
#define LDB   520            // bf16 per LDS B row: 512 + 8 pad -> 260 dwords stride.
                             // 260 % 32 == 4 -> ds_read_b128 conflict-free.
#define TEMP  0.1f
#define ROWS_PER_BLOCK 256
#define THREADS 1024

// 256 blocks (1/CU, LDS-limited) x 16 waves. B (prototypes) persistent in LDS.
// Each wave owns 16 rows x all 128 prototypes; NO barriers in the main loop.
// R4: labels moved to TAIL of the VMEM stream (vmcnt drains in-order, so the
//     old head placement forced every early A-wait to drain 32 scattered
//     label loads; tail placement also frees 32 VGPRs across the main loop).
//     A-prefetch deepened to distance-3 (6 KB in flight/wave), full unroll,
//     dual ss chains, b128 staging stores, __logf epilogue.
__global__ __launch_bounds__(THREADS, 4)
void mrc_fused(const float* __restrict__ bfeat,
               const float* __restrict__ protos,
               const int*   __restrict__ labels,
               const float* __restrict__ weights,
               float*       __restrict__ out,
               int nrows)
{
    __shared__ __bf16 sB[P_DIM * LDB];   // 133120 B
    __shared__ float  sRed[16];

    const int t    = threadIdx.x;
    const int lane = t & 63;
    const int wave = t >> 6;
    const int q    = lane >> 4;   // quad 0..3
    const int cl   = lane & 15;

    const long long r0 = (long long)blockIdx.x * ROWS_PER_BLOCK + wave * 16;

    // ---- stage prototypes fp32 -> bf16 into LDS, once per block ----
    // 8 iterations x 8 floats/thread, ds_write_b128 (row base 1040 B, 16B-aligned).
#pragma unroll
    for (int i = 0; i < 8; ++i) {
        const int f   = i * THREADS + t;     // 0..8191 groups of 8 floats
        const int row = f >> 6;              // /64 groups per 512-float row
        const int c8  = f & 63;
        const f32x4 v0 = *(const f32x4*)(protos + row * D_DIM + c8 * 8);
        const f32x4 v1 = *(const f32x4*)(protos + row * D_DIM + c8 * 8 + 4);
        bf16x8v b;
        b[0] = (__bf16)v0[0]; b[1] = (__bf16)v0[1]; b[2] = (__bf16)v0[2]; b[3] = (__bf16)v0[3];
        b[4] = (__bf16)v1[0]; b[5] = (__bf16)v1[1]; b[6] = (__bf16)v1[2]; b[7] = (__bf16)v1[3];
        *(bf16x8v*)&sB[row * LDB + c8 * 8] = b;
    }
    __syncthreads();   // the only block-wide barrier before the final reduction

    // ---- each wave: 16 rows, direct global->register A fragments ----
    // A-operand layout for mfma_f32_16x16x32_bf16: A[m = lane&15][k = q*8 + j]
    const float* arow  = bfeat + (r0 + cl) * (long long)D_DIM + q * 8;
    const int*   lbase = labels + r0 * (long long)P_DIM + q * 4 * P_DIM + cl;

    float wcol[8];
#pragma unroll
    for (int ct = 0; ct < 8; ++ct) wcol[ct] = weights[ct * 16 + cl];

    f32x4 acc[8];
#pragma unroll
    for (int ct = 0; ct < 8; ++ct) acc[ct] = (f32x4){0.f, 0.f, 0.f, 0.f};

    // distance-3 prefetch: 6 float4 (6 KB/wave) in flight
    f32x4 pa[3], pb[3];
#pragma unroll
    for (int i = 0; i < 3; ++i) {
        pa[i] = __builtin_nontemporal_load((const f32x4*)(arow + i * 32));
        pb[i] = __builtin_nontemporal_load((const f32x4*)(arow + i * 32 + 4));
    }

    int lab[4][8];                 // filled late in the loop (tail of VMEM stream)
    float ss0 = 0.f, ss1 = 0.f;

#pragma unroll
    for (int ks = 0; ks < 16; ++ks) {          // full unroll: ks%3 is compile-time
        const f32x4 c0 = pa[ks % 3], c1 = pb[ks % 3];
        if (ks < 13) {
            pa[ks % 3] = __builtin_nontemporal_load((const f32x4*)(arow + (ks + 3) * 32));
            pb[ks % 3] = __builtin_nontemporal_load((const f32x4*)(arow + (ks + 3) * 32 + 4));
        }
        // label loads issued AFTER (almost) all A loads: no A-wait ever drains them.
        // Split in two halves to flatten VGPR liveness; lane(cl,q) needs
        // labels[row = q*4+reg][col = ct*16+cl], consumed only in the epilogue.
        if (ks == 12) {
#pragma unroll
            for (int reg = 0; reg < 2; ++reg)
#pragma unroll
                for (int ct = 0; ct < 8; ++ct)
                    lab[reg][ct] = __builtin_nontemporal_load(lbase + reg * P_DIM + ct * 16);
        }
        if (ks == 14) {
#pragma unroll
            for (int reg = 2; reg < 4; ++reg)
#pragma unroll
                for (int ct = 0; ct < 8; ++ct)
                    lab[reg][ct] = __builtin_nontemporal_load(lbase + reg * P_DIM + ct * 16);
        }
        ss0 += c0[0]*c0[0] + c0[1]*c0[1] + c0[2]*c0[2] + c0[3]*c0[3];
        ss1 += c1[0]*c1[0] + c1[1]*c1[1] + c1[2]*c1[2] + c1[3]*c1[3];
        bf16x8v af;
        af[0]=(__bf16)c0[0]; af[1]=(__bf16)c0[1]; af[2]=(__bf16)c0[2]; af[3]=(__bf16)c0[3];
        af[4]=(__bf16)c1[0]; af[5]=(__bf16)c1[1]; af[6]=(__bf16)c1[2]; af[7]=(__bf16)c1[3];
        const int k0 = ks * 32 + q * 8;
#pragma unroll
        for (int ct = 0; ct < 8; ++ct) {
            const bf16x8v bfr = *(const bf16x8v*)&sB[(ct * 16 + cl) * LDB + k0];
            acc[ct] = __builtin_amdgcn_mfma_f32_16x16x32_bf16(af, bfr, acc[ct], 0, 0, 0);
        }
    }

    // ---- row norms: lane(cl,q) holds 128 of row cl's 512 squares ----
    float ss = ss0 + ss1;
    ss += __shfl_xor(ss, 16);
    ss += __shfl_xor(ss, 32);
    const float scale = 1.0f / (fmaxf(sqrtf(ss), 1e-12f) * TEMP);  // for row cl

    // ---- epilogue: masked log-softmax per row ----
    // C/D layout: col = ct*16 + (lane&15), row = q*4 + reg
    float pos_acc = 0.f;
#pragma unroll
    for (int reg = 0; reg < 4; ++reg) {
        const float rscale = __shfl(scale, q * 4 + reg, 16);  // scale lives in lane cl==row
        float lg[8];
        float m = -3.4e38f;
#pragma unroll
        for (int ct = 0; ct < 8; ++ct) {
            lg[ct] = acc[ct][reg] * rscale;
            m = fmaxf(m, lg[ct]);
        }
        m = fmaxf(m, __shfl_xor(m, 1, 16));
        m = fmaxf(m, __shfl_xor(m, 2, 16));
        m = fmaxf(m, __shfl_xor(m, 4, 16));
        m = fmaxf(m, __shfl_xor(m, 8, 16));

        float s = 0.f, pz = 0.f, msum = 0.f;
#pragma unroll
        for (int ct = 0; ct < 8; ++ct) {
            const float mask = (float)lab[reg][ct] * wcol[ct];
            const float z = lg[ct] - m;
            s    += __expf(z) * (1.0f - mask);
            pz   += mask * z;
            msum += mask;
        }
        s += __shfl_xor(s, 1, 16);
        s += __shfl_xor(s, 2, 16);
        s += __shfl_xor(s, 4, 16);
        s += __shfl_xor(s, 8, 16);
        // sum(mask*(z - log S)) = sum(mask*z) - log(S)*sum(mask)
        pos_acc += pz - __logf(s) * msum;
    }

    // ---- block reduction -> one atomicAdd ----
    pos_acc += __shfl_xor(pos_acc, 1);
    pos_acc += __shfl_xor(pos_acc, 2);
    pos_acc += __shfl_xor(pos_acc, 4);
    pos_acc += __shfl_xor(pos_acc, 8);
    pos_acc += __shfl_xor(pos_acc, 16);
    pos_acc += __shfl_xor(pos_acc, 32);
    if (lane == 0) sRed[wave] = pos_acc;
    __syncthreads();
    if (t == 0) {
        float total = 0.f;
#pragma unroll
        for (int w = 0; w < 16; ++w) total += sRed[w];
        // loss = LAMBDA * (-(T/BT) * sum(mean_log_prob_pos)) / n ; LAMBDA=1, BT=1
        atomicAdd(out, total * (-TEMP / (float)nrows));
    }
}

extern "C" void kernel_launch(void* const* d_in, const int* in_sizes, int n_in,
                              void* d_out, int out_size, void* d_ws, size_t ws_size,
                              hipStream_t stream) {
    const float* bfeat   = (const float*)d_in[2];
    const float* protos  = (const float*)d_in[3];
    const int*   labels  = (const int*)d_in[4];
    const float* weights = (const float*)d_in[5];
    float* out = (float*)d_out;

    const int nrows = in_sizes[2] / D_DIM;         // 65536

    hipMemsetAsync(d_out, 0, sizeof(float) * out_size, stream);
    const int nblocks = nrows / ROWS_PER_BLOCK;    // 256
    mrc_fused<<<nblocks, THREADS, 0, stream>>>(bfeat, protos, labels, weights, out, nrows);
}

// Round 2
// 238.495 us; speedup vs baseline: 1.0723x; 1.0090x over previous
//
#include <hip/hip_runtime.h>
#include <hip/hip_bf16.h>
#include <math.h>

typedef __bf16 bf16x8v __attribute__((ext_vector_type(8)));
typedef __bf16 bf16x4v __attribute__((ext_vector_type(4)));
typedef float  f32x4   __attribute__((ext_vector_type(4)));

#define D_DIM 512
#define P_DIM 128
#define LDB   520            // bf16 per LDS B row: 512 + 8 pad -> 260 dwords stride.
                             // 260 % 32 == 4 -> ds_read_b128 conflict-free.
#define TEMP  0.1f
#define ROWS_PER_BLOCK 256
#define THREADS 1024

// 256 blocks (1/CU, LDS-limited) x 16 waves. B (prototypes) persistent in LDS.
// Each wave owns 16 rows x all 128 prototypes; NO barriers in the main loop.
// R5: A-prefetch + weights hoisted ABOVE the proto-staging loop, so the HBM
//     A-stream is already in flight while protos stage through L2 and the
//     barrier settles (block startup = max(A-latency, staging), not the sum).
//     Labels remain at the TAIL of the VMEM stream (ks 12/14) so no A-wait
//     ever drains them. Distance-3 prefetch, full unroll, dual ss chains.
__global__ __launch_bounds__(THREADS, 4)
void mrc_fused(const float* __restrict__ bfeat,
               const float* __restrict__ protos,
               const int*   __restrict__ labels,
               const float* __restrict__ weights,
               float*       __restrict__ out,
               int nrows)
{
    __shared__ __bf16 sB[P_DIM * LDB];   // 133120 B
    __shared__ float  sRed[16];

    const int t    = threadIdx.x;
    const int lane = t & 63;
    const int wave = t >> 6;
    const int q    = lane >> 4;   // quad 0..3
    const int cl   = lane & 15;

    const long long r0 = (long long)blockIdx.x * ROWS_PER_BLOCK + wave * 16;

    // ---- A-operand pointers, issued FIRST so the HBM stream starts now ----
    // A layout for mfma_f32_16x16x32_bf16: A[m = lane&15][k = q*8 + j]
    const float* arow  = bfeat + (r0 + cl) * (long long)D_DIM + q * 8;
    const int*   lbase = labels + r0 * (long long)P_DIM + q * 4 * P_DIM + cl;

    // distance-3 prefetch: 6 float4 (6 KB/wave, 96 KB/CU) in flight before staging
    f32x4 pa[3], pb[3];
#pragma unroll
    for (int i = 0; i < 3; ++i) {
        pa[i] = __builtin_nontemporal_load((const f32x4*)(arow + i * 32));
        pb[i] = __builtin_nontemporal_load((const f32x4*)(arow + i * 32 + 4));
    }
    float wcol[8];
#pragma unroll
    for (int ct = 0; ct < 8; ++ct) wcol[ct] = weights[ct * 16 + cl];

    // ---- stage prototypes fp32 -> bf16 into LDS, once per block ----
    // 8 iterations x 8 floats/thread, ds_write_b128 (row base 1040 B, 16B-aligned).
    // The vmcnt waits here drain the (older) A prefetches too -- harmless, they
    // are useful work already arriving while protos come from L2.
#pragma unroll
    for (int i = 0; i < 8; ++i) {
        const int f   = i * THREADS + t;     // 0..8191 groups of 8 floats
        const int row = f >> 6;              // /64 groups per 512-float row
        const int c8  = f & 63;
        const f32x4 v0 = *(const f32x4*)(protos + row * D_DIM + c8 * 8);
        const f32x4 v1 = *(const f32x4*)(protos + row * D_DIM + c8 * 8 + 4);
        bf16x8v b;
        b[0] = (__bf16)v0[0]; b[1] = (__bf16)v0[1]; b[2] = (__bf16)v0[2]; b[3] = (__bf16)v0[3];
        b[4] = (__bf16)v1[0]; b[5] = (__bf16)v1[1]; b[6] = (__bf16)v1[2]; b[7] = (__bf16)v1[3];
        *(bf16x8v*)&sB[row * LDB + c8 * 8] = b;
    }
    __syncthreads();   // the only block-wide barrier before the final reduction

    f32x4 acc[8];
#pragma unroll
    for (int ct = 0; ct < 8; ++ct) acc[ct] = (f32x4){0.f, 0.f, 0.f, 0.f};

    int lab[4][8];                 // filled late in the loop (tail of VMEM stream)
    float ss0 = 0.f, ss1 = 0.f;

#pragma unroll
    for (int ks = 0; ks < 16; ++ks) {          // full unroll: ks%3 is compile-time
        const f32x4 c0 = pa[ks % 3], c1 = pb[ks % 3];
        if (ks < 13) {
            pa[ks % 3] = __builtin_nontemporal_load((const f32x4*)(arow + (ks + 3) * 32));
            pb[ks % 3] = __builtin_nontemporal_load((const f32x4*)(arow + (ks + 3) * 32 + 4));
        }
        // label loads issued AFTER (almost) all A loads: no A-wait ever drains them.
        // Split in two halves to flatten VGPR liveness; lane(cl,q) needs
        // labels[row = q*4+reg][col = ct*16+cl], consumed only in the epilogue.
        if (ks == 12) {
#pragma unroll
            for (int reg = 0; reg < 2; ++reg)
#pragma unroll
                for (int ct = 0; ct < 8; ++ct)
                    lab[reg][ct] = __builtin_nontemporal_load(lbase + reg * P_DIM + ct * 16);
        }
        if (ks == 14) {
#pragma unroll
            for (int reg = 2; reg < 4; ++reg)
#pragma unroll
                for (int ct = 0; ct < 8; ++ct)
                    lab[reg][ct] = __builtin_nontemporal_load(lbase + reg * P_DIM + ct * 16);
        }
        ss0 += c0[0]*c0[0] + c0[1]*c0[1] + c0[2]*c0[2] + c0[3]*c0[3];
        ss1 += c1[0]*c1[0] + c1[1]*c1[1] + c1[2]*c1[2] + c1[3]*c1[3];
        bf16x8v af;
        af[0]=(__bf16)c0[0]; af[1]=(__bf16)c0[1]; af[2]=(__bf16)c0[2]; af[3]=(__bf16)c0[3];
        af[4]=(__bf16)c1[0]; af[5]=(__bf16)c1[1]; af[6]=(__bf16)c1[2]; af[7]=(__bf16)c1[3];
        const int k0 = ks * 32 + q * 8;
#pragma unroll
        for (int ct = 0; ct < 8; ++ct) {
            const bf16x8v bfr = *(const bf16x8v*)&sB[(ct * 16 + cl) * LDB + k0];
            acc[ct] = __builtin_amdgcn_mfma_f32_16x16x32_bf16(af, bfr, acc[ct], 0, 0, 0);
        }
    }

    // ---- row norms: lane(cl,q) holds 128 of row cl's 512 squares ----
    float ss = ss0 + ss1;
    ss += __shfl_xor(ss, 16);
    ss += __shfl_xor(ss, 32);
    const float scale = 1.0f / (fmaxf(sqrtf(ss), 1e-12f) * TEMP);  // for row cl

    // ---- epilogue: masked log-softmax per row ----
    // C/D layout: col = ct*16 + (lane&15), row = q*4 + reg
    float pos_acc = 0.f;
#pragma unroll
    for (int reg = 0; reg < 4; ++reg) {
        const float rscale = __shfl(scale, q * 4 + reg, 16);  // scale lives in lane cl==row
        float lg[8];
        float m = -3.4e38f;
#pragma unroll
        for (int ct = 0; ct < 8; ++ct) {
            lg[ct] = acc[ct][reg] * rscale;
            m = fmaxf(m, lg[ct]);
        }
        m = fmaxf(m, __shfl_xor(m, 1, 16));
        m = fmaxf(m, __shfl_xor(m, 2, 16));
        m = fmaxf(m, __shfl_xor(m, 4, 16));
        m = fmaxf(m, __shfl_xor(m, 8, 16));

        float s = 0.f, pz = 0.f, msum = 0.f;
#pragma unroll
        for (int ct = 0; ct < 8; ++ct) {
            const float mask = (float)lab[reg][ct] * wcol[ct];
            const float z = lg[ct] - m;
            s    += __expf(z) * (1.0f - mask);
            pz   += mask * z;
            msum += mask;
        }
        s += __shfl_xor(s, 1, 16);
        s += __shfl_xor(s, 2, 16);
        s += __shfl_xor(s, 4, 16);
        s += __shfl_xor(s, 8, 16);
        // sum(mask*(z - log S)) = sum(mask*z) - log(S)*sum(mask)
        pos_acc += pz - __logf(s) * msum;
    }

    // ---- block reduction -> one atomicAdd ----
    pos_acc += __shfl_xor(pos_acc, 1);
    pos_acc += __shfl_xor(pos_acc, 2);
    pos_acc += __shfl_xor(pos_acc, 4);
    pos_acc += __shfl_xor(pos_acc, 8);
    pos_acc += __shfl_xor(pos_acc, 16);
    pos_acc += __shfl_xor(pos_acc, 32);
    if (lane == 0) sRed[wave] = pos_acc;
    __syncthreads();
    if (t == 0) {
        float total = 0.f;
#pragma unroll
        for (int w = 0; w < 16; ++w) total += sRed[w];
        // loss = LAMBDA * (-(T/BT) * sum(mean_log_prob_pos)) / n ; LAMBDA=1, BT=1
        atomicAdd(out, total * (-TEMP / (float)nrows));
    }
}

extern "C" void kernel_launch(void* const* d_in, const int* in_sizes, int n_in,
                              void* d_out, int out_size, void* d_ws, size_t ws_size,
                              hipStream_t stream) {
    const float* bfeat   = (const float*)d_in[2];
    const float* protos  = (const float*)d_in[3];
    const int*   labels  = (const int*)d_in[4];
    const float* weights = (const float*)d_in[5];
    float* out = (float*)d_out;

    const int nrows = in_sizes[2] / D_DIM;         // 65536

    hipMemsetAsync(d_out, 0, sizeof(float) * out_size, stream);
    const int nblocks = nrows / ROWS_PER_BLOCK;    // 256
    mrc_fused<<<nblocks, THREADS, 0, stream>>>(bfeat, protos, labels, weights, out, nrows);
}